// Round 18
// baseline (1722.321 us; speedup 1.0000x reference)
//
#include <hip/hip_runtime.h>

// RLIF forward, persistent kernel, stamp-in-word sync.
// Round 18 = Round 16 (PASS @929us) with the SAME lever pushed further:
// fold 2 wgs into 1 -> 128 wgs x 512 threads (8 waves = 4 ct x 2 h).
//  - wg = 16 batches x 64 neurons; group = 16 wgs (was 32 producers -> 16)
//  - 1024 stamped words / 512 threads -> guarded poll chain 2 (was 4)
//  - per-wave compute identical to R16: 48 MFMA, M=16 full, 192 Wr VGPRs
//    (2 waves/SIMD x 256 VGPR budget fits the ~232 used)
//  - half the CUs idle: fine, the kernel is latency-bound not throughput-bound
// Poll shape (guarded serialized + sleep(1) -- 6x-validated best), publish
// (atomicExch (t<<16)|bits16, triple buffer), A-frag bits, mat-outer/ks-inner
// chain, z = acc_h0 + red_h1, epilogue order: bit-identical per output element.

#define T_STEPS 256
#define BATCH   128
#define NNEUR   1024
#define DECAY_F 0.2f
#define THRESH  0.3f

typedef __attribute__((ext_vector_type(8))) short short8;
typedef __attribute__((ext_vector_type(4))) float f32x4;

union FU { short8 s; unsigned u[4]; };
union S8 { short8 s; unsigned short us[8]; };

__device__ __forceinline__ unsigned short f2bf_rn(float x) {
    unsigned u = __float_as_uint(x);
    return (unsigned short)((u + 0x7FFFu + ((u >> 16) & 1u)) >> 16);
}

__global__ void rlif_init(unsigned* __restrict__ ybits) {
    int i = blockIdx.x * 256 + threadIdx.x;
    if (i < 3 * 8 * 1024) ybits[i] = 0xFFFF0000u;   // stamp 0xFFFF: never matches t
}

__global__ __launch_bounds__(512, 1)
void rlif_persist(const float* __restrict__ tx,   // [T][B][N]
                  const float* __restrict__ Wr,   // [N][N]
                  const float* __restrict__ br,   // [N]
                  float* __restrict__ out,        // [T][B][N]
                  unsigned* __restrict__ ybits)   // [3][8 grp][16 row][64 col] stamped
{
    extern __shared__ char smem[];
    float* red = (float*)smem;                                // [4 ct][16][16] f32
    unsigned short* ys = (unsigned short*)(smem + 4*16*16*4); // [16][66]

    const int tid = threadIdx.x;
    const int bb  = blockIdx.x >> 4;   // 0..7  batch-block (16 batches)
    const int ib  = blockIdx.x & 15;   // 0..15 neuron-block (64 neurons)
    const int i0  = ib * 64;
    const int b0  = bb * 16;
    const int w   = tid >> 6;          // wave 0..7
    const int l   = tid & 63;
    const int c   = l & 15;
    const int kg  = l >> 4;
    const int ct  = w & 3;             // neuron sub-tile (16 neurons)
    const int h   = w >> 2;            // k-half

    // ---- one-time: this lane's Wr B-fragments, exact 3-way bf16 split, in regs ----
    short8 fr0[16], fr1[16], fr2[16];
    {
        const float* wrow = Wr + (size_t)(i0 + ct * 16 + c) * NNEUR + h * 512 + kg * 8;
        #pragma unroll
        for (int ks = 0; ks < 16; ++ks) {
            float4 a = *(const float4*)(wrow + ks * 32);
            float4 b = *(const float4*)(wrow + ks * 32 + 4);
            float fv[8] = {a.x, a.y, a.z, a.w, b.x, b.y, b.z, b.w};
            S8 vh, vm, vl;
            #pragma unroll
            for (int e = 0; e < 8; ++e) {
                float fw = fv[e];
                unsigned short hb = f2bf_rn(fw);
                float hf = __uint_as_float((unsigned)hb << 16);
                float rm = fw - hf;                     // exact (Sterbenz)
                unsigned short mb = f2bf_rn(rm);
                float mf = __uint_as_float((unsigned)mb << 16);
                float rl = rm - mf;                     // exact; fits bf16
                vh.us[e] = hb; vm.us[e] = mb; vl.us[e] = f2bf_rn(rl);
            }
            fr0[ks] = vh.s; fr1[ks] = vm.s; fr2[ks] = vl.s;
        }
    }
    __syncthreads();

    const float brv = br[i0 + ct * 16 + c];
    float vreg[4] = {0.f, 0.f, 0.f, 0.f};
    const size_t BN = (size_t)BATCH * NNEUR;

    for (int t = 0; t < T_STEPS; ++t) {
        float txv[4];
        if (h == 0) {
            #pragma unroll
            for (int j = 0; j < 4; ++j)
                txv[j] = tx[(size_t)t * BN + (size_t)(b0 + kg * 4 + j) * NNEUR + i0 + ct * 16 + c];
        }

        // ---- stage spikes of step t-1 into LDS (R6/R16 poll shape, chain of 2) ----
        if (t > 0) {
            unsigned* buf = ybits + (size_t)((t - 1) % 3) * (8 * 1024) + bb * 1024;
            const unsigned want = (unsigned)(t - 1);
            unsigned pend = 0x3u;     // 2 words per thread: wi = k*512 + tid
            for (;;) {
                #pragma unroll
                for (int k = 0; k < 2; ++k) {
                    if (pend & (1u << k)) {
                        int wi  = (k << 9) | tid;       // 0..1023
                        int row = wi >> 6;              // 0..15 (batch within block)
                        int col = wi & 63;              // writer column (ib*4+ct)
                        unsigned v = __hip_atomic_load(&buf[row * 64 + col],
                                                       __ATOMIC_RELAXED, __HIP_MEMORY_SCOPE_AGENT);
                        if ((v >> 16) == want) {
                            ys[row * 66 + col] = (unsigned short)(v & 0xFFFFu);
                            pend &= ~(1u << k);
                        }
                    }
                }
                if (!pend) break;
                __builtin_amdgcn_s_sleep(1);
            }
        }
        __syncthreads();

        f32x4 acc = {0.f, 0.f, 0.f, 0.f};
        if (t > 0) {
            // A-frags: bf16 1.0 / 0.0 bit patterns (identical to rounds 2/5/6/14/16)
            short8 afr[16];
            #pragma unroll
            for (int ks = 0; ks < 16; ++ks) {
                unsigned wv = *(const unsigned*)(ys + c * 66 + 2 * (h * 16 + ks));
                unsigned byt = (wv >> (kg * 8)) & 0xFFu;
                FU f;
                #pragma unroll
                for (int q = 0; q < 4; ++q) {
                    f.u[q] = (((byt >> (2 * q)) & 1u) ? 0x00003F80u : 0u)
                           | (((byt >> (2 * q + 1)) & 1u) ? 0x3F800000u : 0u);
                }
                afr[ks] = f.s;
            }
            // single accumulator chain, mat-outer / ks-inner — proven exact order
            #pragma unroll
            for (int ks = 0; ks < 16; ++ks)
                acc = __builtin_amdgcn_mfma_f32_16x16x32_bf16(afr[ks], fr0[ks], acc, 0, 0, 0);
            #pragma unroll
            for (int ks = 0; ks < 16; ++ks)
                acc = __builtin_amdgcn_mfma_f32_16x16x32_bf16(afr[ks], fr1[ks], acc, 0, 0, 0);
            #pragma unroll
            for (int ks = 0; ks < 16; ++ks)
                acc = __builtin_amdgcn_mfma_f32_16x16x32_bf16(afr[ks], fr2[ks], acc, 0, 0, 0);
        }

        if (h == 1) {
            #pragma unroll
            for (int j = 0; j < 4; ++j)
                red[ct * 256 + (kg * 4 + j) * 16 + c] = acc[j];
        }
        __syncthreads();

        if (h == 0) {
            float* op = out + (size_t)t * BN;
            unsigned* pbuf = ybits + (size_t)(t % 3) * (8 * 1024) + bb * 1024;
            #pragma unroll
            for (int j = 0; j < 4; ++j) {
                float z  = acc[j] + red[ct * 256 + (kg * 4 + j) * 16 + c];
                float x  = (txv[j] + z) + brv;
                float vv = DECAY_F * vreg[j] + x;
                int   sp = vv > THRESH;
                vreg[j]  = sp ? 0.f : vv;
                op[(size_t)(b0 + kg * 4 + j) * NNEUR + i0 + ct * 16 + c] = sp ? 1.f : 0.f;
                unsigned long long m = __ballot(sp != 0);
                if (c == j) {
                    unsigned u16v = (unsigned)((m >> (kg * 16)) & 0xFFFFu);
                    atomicExch(&pbuf[(kg * 4 + j) * 64 + ib * 4 + ct],
                               ((unsigned)t << 16) | u16v);
                }
            }
        }
        // no end-of-step barrier: stamp polling is the synchronization
    }
}

extern "C" void kernel_launch(void* const* d_in, const int* in_sizes, int n_in,
                              void* d_out, int out_size, void* d_ws, size_t ws_size,
                              hipStream_t stream)
{
    const float* tx = (const float*)d_in[0];
    const float* Wr = (const float*)d_in[1];
    const float* br = (const float*)d_in[2];
    float* out = (float*)d_out;
    unsigned* ybits = (unsigned*)d_ws;   // [3][8][1024] u32 = 96 KB

    const int lds_bytes = 4 * 16 * 16 * 4 + 16 * 66 * 2;   // 6208
    hipFuncSetAttribute(reinterpret_cast<const void*>(rlif_persist),
                        hipFuncAttributeMaxDynamicSharedMemorySize, lds_bytes);

    rlif_init<<<dim3(96), dim3(256), 0, stream>>>(ybits);
    rlif_persist<<<dim3(128), dim3(512), lds_bytes, stream>>>(tx, Wr, br, out, ybits);
}

// Round 19
// 1278.046 us; speedup vs baseline: 1.3476x; 1.3476x over previous
//
#include <hip/hip_runtime.h>

// RLIF forward, persistent kernel, stamp-in-word sync.
// Round 19 = Round 16 (PASS @929us, 8x32 geometry, register-Wr) with ONE change:
// consumer polls u64 QWORDS (two adjacent stamped u32 words per load, both
// stamps verified -- the dual-stamp read validated in R8/R10). 512 qwords /
// 256 threads -> guarded chain 2 (was 4). Adjacent cols (2i,2i+1) are the SAME
// producer wg's ct=0/ct=1 waves (same epilogue) -> ~zero added skew per qword.
//  - R18's chain-2 attempt regressed ONLY from a VGPR spill (512-thr block
//    capped VGPR at 128 < 192 needed; scratch traffic). This keeps 256-thr
//    blocks and VGPR ~228 intact.
// Poll shape (guarded serialized, pending-only, s_sleep(1)), publish
// (atomicExch (t<<16)|bits16, triple buffer), datapath (register 3-split Wr,
// A-frag bits, mat-outer/ks-inner chain, z=acc_h0+red_h1, epilogue order):
// byte-identical to R16 -> bit-identical output.

#define T_STEPS 256
#define BATCH   128
#define NNEUR   1024
#define DECAY_F 0.2f
#define THRESH  0.3f

typedef __attribute__((ext_vector_type(8))) short short8;
typedef __attribute__((ext_vector_type(4))) float f32x4;

union FU { short8 s; unsigned u[4]; };
union S8 { short8 s; unsigned short us[8]; };

__device__ __forceinline__ unsigned short f2bf_rn(float x) {
    unsigned u = __float_as_uint(x);
    return (unsigned short)((u + 0x7FFFu + ((u >> 16) & 1u)) >> 16);
}

__global__ void rlif_init(unsigned* __restrict__ ybits) {
    int i = blockIdx.x * 256 + threadIdx.x;
    if (i < 3 * 8 * 1024) ybits[i] = 0xFFFF0000u;   // stamp 0xFFFF: never matches t
}

__global__ __launch_bounds__(256, 1)
void rlif_persist(const float* __restrict__ tx,   // [T][B][N]
                  const float* __restrict__ Wr,   // [N][N]
                  const float* __restrict__ br,   // [N]
                  float* __restrict__ out,        // [T][B][N]
                  unsigned* __restrict__ ybits)   // [3][8 grp][16 row][64 col] stamped
{
    extern __shared__ char smem[];
    float* red = (float*)smem;                                // [2 ct][16][16] f32
    unsigned short* ys = (unsigned short*)(smem + 2*16*16*4); // [16][66]

    const int tid = threadIdx.x;
    const int bb  = blockIdx.x >> 5;   // 0..7  batch-block (16 batches)
    const int ib  = blockIdx.x & 31;   // 0..31 neuron-block (32 neurons)
    const int i0  = ib * 32;
    const int b0  = bb * 16;
    const int w   = tid >> 6;          // wave 0..3
    const int l   = tid & 63;
    const int c   = l & 15;
    const int kg  = l >> 4;
    const int ct  = w & 1;             // neuron sub-tile (16 neurons)
    const int h   = w >> 1;            // k-half

    // ---- one-time: this lane's Wr B-fragments, exact 3-way bf16 split, in regs ----
    short8 fr0[16], fr1[16], fr2[16];
    {
        const float* wrow = Wr + (size_t)(i0 + ct * 16 + c) * NNEUR + h * 512 + kg * 8;
        #pragma unroll
        for (int ks = 0; ks < 16; ++ks) {
            float4 a = *(const float4*)(wrow + ks * 32);
            float4 b = *(const float4*)(wrow + ks * 32 + 4);
            float fv[8] = {a.x, a.y, a.z, a.w, b.x, b.y, b.z, b.w};
            S8 vh, vm, vl;
            #pragma unroll
            for (int e = 0; e < 8; ++e) {
                float fw = fv[e];
                unsigned short hb = f2bf_rn(fw);
                float hf = __uint_as_float((unsigned)hb << 16);
                float rm = fw - hf;                     // exact (Sterbenz)
                unsigned short mb = f2bf_rn(rm);
                float mf = __uint_as_float((unsigned)mb << 16);
                float rl = rm - mf;                     // exact; fits bf16
                vh.us[e] = hb; vm.us[e] = mb; vl.us[e] = f2bf_rn(rl);
            }
            fr0[ks] = vh.s; fr1[ks] = vm.s; fr2[ks] = vl.s;
        }
    }
    __syncthreads();

    const float brv = br[i0 + ct * 16 + c];
    float vreg[4] = {0.f, 0.f, 0.f, 0.f};
    const size_t BN = (size_t)BATCH * NNEUR;

    for (int t = 0; t < T_STEPS; ++t) {
        float txv[4];
        if (h == 0) {
            #pragma unroll
            for (int j = 0; j < 4; ++j)
                txv[j] = tx[(size_t)t * BN + (size_t)(b0 + kg * 4 + j) * NNEUR + i0 + ct * 16 + c];
        }

        // ---- stage spikes of step t-1: guarded qword poll, chain of 2 ----
        if (t > 0) {
            const unsigned long long* qb = (const unsigned long long*)
                (ybits + (size_t)((t - 1) % 3) * (8 * 1024) + bb * 1024);
            const unsigned want = (unsigned)(t - 1);
            unsigned pend = 0x3u;     // 2 qwords per thread: wi = k*256 + tid
            for (;;) {
                #pragma unroll
                for (int k = 0; k < 2; ++k) {
                    if (pend & (1u << k)) {
                        int wi  = (k << 8) | tid;       // 0..511
                        int row = wi >> 5;              // 0..15 (batch within block)
                        int qc  = wi & 31;              // qword col (pair of u32 cols)
                        unsigned long long q = __hip_atomic_load(qb + row * 32 + qc,
                                                                 __ATOMIC_RELAXED, __HIP_MEMORY_SCOPE_AGENT);
                        unsigned lo = (unsigned)q;
                        unsigned hi = (unsigned)(q >> 32);
                        if (((lo >> 16) == want) & ((hi >> 16) == want)) {
                            *(unsigned*)&ys[row * 66 + 2 * qc] = (lo & 0xFFFFu) | (hi << 16);
                            pend &= ~(1u << k);
                        }
                    }
                }
                if (!pend) break;
                __builtin_amdgcn_s_sleep(1);
            }
        }
        __syncthreads();

        f32x4 acc = {0.f, 0.f, 0.f, 0.f};
        if (t > 0) {
            // A-frags: bf16 1.0 / 0.0 bit patterns (identical to rounds 2/5/6/14/16)
            short8 afr[16];
            #pragma unroll
            for (int ks = 0; ks < 16; ++ks) {
                unsigned wv = *(const unsigned*)(ys + c * 66 + 2 * (h * 16 + ks));
                unsigned byt = (wv >> (kg * 8)) & 0xFFu;
                FU f;
                #pragma unroll
                for (int q = 0; q < 4; ++q) {
                    f.u[q] = (((byt >> (2 * q)) & 1u) ? 0x00003F80u : 0u)
                           | (((byt >> (2 * q + 1)) & 1u) ? 0x3F800000u : 0u);
                }
                afr[ks] = f.s;
            }
            // single accumulator chain, mat-outer / ks-inner — proven exact order
            #pragma unroll
            for (int ks = 0; ks < 16; ++ks)
                acc = __builtin_amdgcn_mfma_f32_16x16x32_bf16(afr[ks], fr0[ks], acc, 0, 0, 0);
            #pragma unroll
            for (int ks = 0; ks < 16; ++ks)
                acc = __builtin_amdgcn_mfma_f32_16x16x32_bf16(afr[ks], fr1[ks], acc, 0, 0, 0);
            #pragma unroll
            for (int ks = 0; ks < 16; ++ks)
                acc = __builtin_amdgcn_mfma_f32_16x16x32_bf16(afr[ks], fr2[ks], acc, 0, 0, 0);
        }

        if (h == 1) {
            #pragma unroll
            for (int j = 0; j < 4; ++j)
                red[ct * 256 + (kg * 4 + j) * 16 + c] = acc[j];
        }
        __syncthreads();

        if (h == 0) {
            float* op = out + (size_t)t * BN;
            unsigned* pbuf = ybits + (size_t)(t % 3) * (8 * 1024) + bb * 1024;
            #pragma unroll
            for (int j = 0; j < 4; ++j) {
                float z  = acc[j] + red[ct * 256 + (kg * 4 + j) * 16 + c];
                float x  = (txv[j] + z) + brv;
                float vv = DECAY_F * vreg[j] + x;
                int   sp = vv > THRESH;
                vreg[j]  = sp ? 0.f : vv;
                op[(size_t)(b0 + kg * 4 + j) * NNEUR + i0 + ct * 16 + c] = sp ? 1.f : 0.f;
                unsigned long long m = __ballot(sp != 0);
                if (c == j) {
                    unsigned u16v = (unsigned)((m >> (kg * 16)) & 0xFFFFu);
                    atomicExch(&pbuf[(kg * 4 + j) * 64 + ib * 2 + ct],
                               ((unsigned)t << 16) | u16v);
                }
            }
        }
        // no end-of-step barrier: stamp polling is the synchronization
    }
}

extern "C" void kernel_launch(void* const* d_in, const int* in_sizes, int n_in,
                              void* d_out, int out_size, void* d_ws, size_t ws_size,
                              hipStream_t stream)
{
    const float* tx = (const float*)d_in[0];
    const float* Wr = (const float*)d_in[1];
    const float* br = (const float*)d_in[2];
    float* out = (float*)d_out;
    unsigned* ybits = (unsigned*)d_ws;   // [3][8][1024] u32 = 96 KB

    const int lds_bytes = 2 * 16 * 16 * 4 + 16 * 66 * 2;   // 4160
    hipFuncSetAttribute(reinterpret_cast<const void*>(rlif_persist),
                        hipFuncAttributeMaxDynamicSharedMemorySize, lds_bytes);

    rlif_init<<<dim3(96), dim3(256), 0, stream>>>(ybits);
    rlif_persist<<<dim3(256), dim3(256), lds_bytes, stream>>>(tx, Wr, br, out, ybits);
}

// Round 20
// 880.580 us; speedup vs baseline: 1.9559x; 1.4514x over previous
//
#include <hip/hip_runtime.h>

// RLIF forward, persistent kernel, stamp-in-word sync.
// Round 20 = Round 16 (PASS @929us, champion) with ONE change: ROW-PAIR u64
// publish -> single-stamp chain-2 poll.
//  - Producer h=0 wave holds mball[0..3] in every lane after its 4 ballots, so
//    lanes c==0/c==2 publish u64 = (t<<32)|row(2a+1)<<16|row(2a): both payload
//    rows from the SAME wave's simultaneous ballots -> no cross-producer
//    coupling (R19's confound), one 32-bit stamp, one atomicExch(u64).
//  - 512 qwords/group / 256 threads -> guarded chain 2. Poll shape preserved:
//    serialized guarded pending-only + s_sleep(1) (no R17 early-sampling),
//    256-thread blocks (no R18 spill).
//  - ys contents, A-frag bits, register 3-split Wr, mat-outer/ks-inner MFMA
//    chain, z=acc_h0+red_h1, epilogue order: bit-identical to R16.
// Discriminators: FETCH <=130MB and dur < 929 confirms chain-RTT model;
// FETCH >=150MB + regression => sampling cadence dominates, revert to R16.

#define T_STEPS 256
#define BATCH   128
#define NNEUR   1024
#define DECAY_F 0.2f
#define THRESH  0.3f

typedef __attribute__((ext_vector_type(8))) short short8;
typedef __attribute__((ext_vector_type(4))) float f32x4;

union FU { short8 s; unsigned u[4]; };
union S8 { short8 s; unsigned short us[8]; };

__device__ __forceinline__ unsigned short f2bf_rn(float x) {
    unsigned u = __float_as_uint(x);
    return (unsigned short)((u + 0x7FFFu + ((u >> 16) & 1u)) >> 16);
}

__global__ void rlif_init(unsigned long long* __restrict__ qbuf) {
    int i = blockIdx.x * 256 + threadIdx.x;
    if (i < 3 * 8 * 512) qbuf[i] = 0xFFFFFFFF00000000ull;  // stamp never matches t
}

__global__ __launch_bounds__(256, 1)
void rlif_persist(const float* __restrict__ tx,   // [T][B][N]
                  const float* __restrict__ Wr,   // [N][N]
                  const float* __restrict__ br,   // [N]
                  float* __restrict__ out,        // [T][B][N]
                  unsigned long long* __restrict__ qbuf) // [3][8 grp][8 rowpair][64 col]
{
    extern __shared__ char smem[];
    float* red = (float*)smem;                                // [2 ct][16][16] f32
    unsigned short* ys = (unsigned short*)(smem + 2*16*16*4); // [16][66]

    const int tid = threadIdx.x;
    const int bb  = blockIdx.x >> 5;   // 0..7  batch-block (16 batches)
    const int ib  = blockIdx.x & 31;   // 0..31 neuron-block (32 neurons)
    const int i0  = ib * 32;
    const int b0  = bb * 16;
    const int w   = tid >> 6;          // wave 0..3
    const int l   = tid & 63;
    const int c   = l & 15;
    const int kg  = l >> 4;
    const int ct  = w & 1;             // neuron sub-tile (16 neurons)
    const int h   = w >> 1;            // k-half

    // ---- one-time: this lane's Wr B-fragments, exact 3-way bf16 split, in regs ----
    short8 fr0[16], fr1[16], fr2[16];
    {
        const float* wrow = Wr + (size_t)(i0 + ct * 16 + c) * NNEUR + h * 512 + kg * 8;
        #pragma unroll
        for (int ks = 0; ks < 16; ++ks) {
            float4 a = *(const float4*)(wrow + ks * 32);
            float4 b = *(const float4*)(wrow + ks * 32 + 4);
            float fv[8] = {a.x, a.y, a.z, a.w, b.x, b.y, b.z, b.w};
            S8 vh, vm, vl;
            #pragma unroll
            for (int e = 0; e < 8; ++e) {
                float fw = fv[e];
                unsigned short hb = f2bf_rn(fw);
                float hf = __uint_as_float((unsigned)hb << 16);
                float rm = fw - hf;                     // exact (Sterbenz)
                unsigned short mb = f2bf_rn(rm);
                float mf = __uint_as_float((unsigned)mb << 16);
                float rl = rm - mf;                     // exact; fits bf16
                vh.us[e] = hb; vm.us[e] = mb; vl.us[e] = f2bf_rn(rl);
            }
            fr0[ks] = vh.s; fr1[ks] = vm.s; fr2[ks] = vl.s;
        }
    }
    __syncthreads();

    const float brv = br[i0 + ct * 16 + c];
    float vreg[4] = {0.f, 0.f, 0.f, 0.f};
    const size_t BN = (size_t)BATCH * NNEUR;

    for (int t = 0; t < T_STEPS; ++t) {
        float txv[4];
        if (h == 0) {
            #pragma unroll
            for (int j = 0; j < 4; ++j)
                txv[j] = tx[(size_t)t * BN + (size_t)(b0 + kg * 4 + j) * NNEUR + i0 + ct * 16 + c];
        }

        // ---- stage spikes of step t-1: single-stamp rowpair qwords, chain of 2 ----
        if (t > 0) {
            const unsigned long long* qb = qbuf + (size_t)((t - 1) % 3) * 4096 + bb * 512;
            const unsigned want = (unsigned)(t - 1);
            unsigned pend = 0x3u;     // 2 qwords per thread: wi = k*256 + tid
            for (;;) {
                #pragma unroll
                for (int k = 0; k < 2; ++k) {
                    if (pend & (1u << k)) {
                        int wi  = (k << 8) | tid;       // 0..511
                        int p   = wi >> 6;              // rowpair 0..7
                        int col = wi & 63;              // writer column (ib*2+ct)
                        unsigned long long q = __hip_atomic_load(&qb[p * 64 + col],
                                                                 __ATOMIC_RELAXED, __HIP_MEMORY_SCOPE_AGENT);
                        if ((unsigned)(q >> 32) == want) {
                            ys[(2 * p) * 66 + col]     = (unsigned short)(q & 0xFFFFu);
                            ys[(2 * p + 1) * 66 + col] = (unsigned short)((q >> 16) & 0xFFFFu);
                            pend &= ~(1u << k);
                        }
                    }
                }
                if (!pend) break;
                __builtin_amdgcn_s_sleep(1);
            }
        }
        __syncthreads();

        f32x4 acc = {0.f, 0.f, 0.f, 0.f};
        if (t > 0) {
            // A-frags: bf16 1.0 / 0.0 bit patterns (identical to rounds 2/5/6/14/16)
            short8 afr[16];
            #pragma unroll
            for (int ks = 0; ks < 16; ++ks) {
                unsigned wv = *(const unsigned*)(ys + c * 66 + 2 * (h * 16 + ks));
                unsigned byt = (wv >> (kg * 8)) & 0xFFu;
                FU f;
                #pragma unroll
                for (int q = 0; q < 4; ++q) {
                    f.u[q] = (((byt >> (2 * q)) & 1u) ? 0x00003F80u : 0u)
                           | (((byt >> (2 * q + 1)) & 1u) ? 0x3F800000u : 0u);
                }
                afr[ks] = f.s;
            }
            // single accumulator chain, mat-outer / ks-inner — proven exact order
            #pragma unroll
            for (int ks = 0; ks < 16; ++ks)
                acc = __builtin_amdgcn_mfma_f32_16x16x32_bf16(afr[ks], fr0[ks], acc, 0, 0, 0);
            #pragma unroll
            for (int ks = 0; ks < 16; ++ks)
                acc = __builtin_amdgcn_mfma_f32_16x16x32_bf16(afr[ks], fr1[ks], acc, 0, 0, 0);
            #pragma unroll
            for (int ks = 0; ks < 16; ++ks)
                acc = __builtin_amdgcn_mfma_f32_16x16x32_bf16(afr[ks], fr2[ks], acc, 0, 0, 0);
        }

        if (h == 1) {
            #pragma unroll
            for (int j = 0; j < 4; ++j)
                red[ct * 256 + (kg * 4 + j) * 16 + c] = acc[j];
        }
        __syncthreads();

        if (h == 0) {
            float* op = out + (size_t)t * BN;
            unsigned long long* pq = qbuf + (size_t)(t % 3) * 4096 + bb * 512;
            int sp4[4];
            unsigned long long mball[4];
            #pragma unroll
            for (int j = 0; j < 4; ++j) {
                float z  = acc[j] + red[ct * 256 + (kg * 4 + j) * 16 + c];
                float x  = (txv[j] + z) + brv;
                float vv = DECAY_F * vreg[j] + x;
                int   sp = vv > THRESH;
                vreg[j]  = sp ? 0.f : vv;
                sp4[j]   = sp;
                mball[j] = __ballot(sp != 0);
            }
            // publish FIRST: rowpair qwords (lanes c==0 -> rows kg*4+0/1, c==2 -> +2/3)
            if (c == 0 || c == 2) {
                int a = c >> 1;
                unsigned lo = (unsigned)((mball[2 * a]     >> (kg * 16)) & 0xFFFFu);
                unsigned hi = (unsigned)((mball[2 * a + 1] >> (kg * 16)) & 0xFFFFu);
                unsigned long long qv = ((unsigned long long)(unsigned)t << 32)
                                      | ((unsigned long long)hi << 16) | lo;
                atomicExch(&pq[(kg * 2 + a) * 64 + ib * 2 + ct], qv);
            }
            // then the out-slab stores (no intra-kernel consumer)
            #pragma unroll
            for (int j = 0; j < 4; ++j)
                op[(size_t)(b0 + kg * 4 + j) * NNEUR + i0 + ct * 16 + c] = sp4[j] ? 1.f : 0.f;
        }
        // no end-of-step barrier: stamp polling is the synchronization
    }
}

extern "C" void kernel_launch(void* const* d_in, const int* in_sizes, int n_in,
                              void* d_out, int out_size, void* d_ws, size_t ws_size,
                              hipStream_t stream)
{
    const float* tx = (const float*)d_in[0];
    const float* Wr = (const float*)d_in[1];
    const float* br = (const float*)d_in[2];
    float* out = (float*)d_out;
    unsigned long long* qbuf = (unsigned long long*)d_ws;   // [3][8][512] u64 = 96 KB

    const int lds_bytes = 2 * 16 * 16 * 4 + 16 * 66 * 2;   // 4160
    hipFuncSetAttribute(reinterpret_cast<const void*>(rlif_persist),
                        hipFuncAttributeMaxDynamicSharedMemorySize, lds_bytes);

    rlif_init<<<dim3(48), dim3(256), 0, stream>>>(qbuf);
    rlif_persist<<<dim3(256), dim3(256), lds_bytes, stream>>>(tx, Wr, br, out, qbuf);
}

// Round 21
// 644.640 us; speedup vs baseline: 2.6718x; 1.3660x over previous
//
#include <hip/hip_runtime.h>

// RLIF forward, persistent kernel, stamp-in-word sync.
// Round 21 = Round 20 (PASS @880us, champion) with ONE change: PAIRED-QWORD
// 16B poll. Publish layout permuted col-major (flat = col*8 + p) so each
// consumer thread's two rowpair qwords are adjacent 16B -> first-pass is ONE
// global_load_dwordx4 sc0 sc1 (1 RTT instead of 2 serialized). Both qwords
// are published by the SAME producer wave (lanes c=0/c=2 of one kg group,
// same epilogue ballots, ~simultaneous exchanges) -> no R17 cross-producer
// early-sampling risk. Each u64 self-stamped (t<<32) -> per-qword verify
// preserved; stragglers re-polled with guarded-serialized 8B atomic loads +
// s_sleep(1) (the proven retry shape).
// Datapath, publish instruction, triple buffer, ys contents, epilogue:
// byte-identical to R20 -> bit-identical output.

#define T_STEPS 256
#define BATCH   128
#define NNEUR   1024
#define DECAY_F 0.2f
#define THRESH  0.3f

typedef __attribute__((ext_vector_type(8))) short short8;
typedef __attribute__((ext_vector_type(4))) float f32x4;
typedef __attribute__((ext_vector_type(4))) unsigned uint4v;

union FU { short8 s; unsigned u[4]; };
union S8 { short8 s; unsigned short us[8]; };

__device__ __forceinline__ unsigned short f2bf_rn(float x) {
    unsigned u = __float_as_uint(x);
    return (unsigned short)((u + 0x7FFFu + ((u >> 16) & 1u)) >> 16);
}

__global__ void rlif_init(unsigned long long* __restrict__ qbuf) {
    int i = blockIdx.x * 256 + threadIdx.x;
    if (i < 3 * 8 * 512) qbuf[i] = 0xFFFFFFFF00000000ull;  // stamp never matches t
}

__global__ __launch_bounds__(256, 1)
void rlif_persist(const float* __restrict__ tx,   // [T][B][N]
                  const float* __restrict__ Wr,   // [N][N]
                  const float* __restrict__ br,   // [N]
                  float* __restrict__ out,        // [T][B][N]
                  unsigned long long* __restrict__ qbuf) // [3][8 grp][64 col][8 rowpair]
{
    extern __shared__ char smem[];
    float* red = (float*)smem;                                // [2 ct][16][16] f32
    unsigned short* ys = (unsigned short*)(smem + 2*16*16*4); // [16][66]

    const int tid = threadIdx.x;
    const int bb  = blockIdx.x >> 5;   // 0..7  batch-block (16 batches)
    const int ib  = blockIdx.x & 31;   // 0..31 neuron-block (32 neurons)
    const int i0  = ib * 32;
    const int b0  = bb * 16;
    const int w   = tid >> 6;          // wave 0..3
    const int l   = tid & 63;
    const int c   = l & 15;
    const int kg  = l >> 4;
    const int ct  = w & 1;             // neuron sub-tile (16 neurons)
    const int h   = w >> 1;            // k-half

    // ---- one-time: this lane's Wr B-fragments, exact 3-way bf16 split, in regs ----
    short8 fr0[16], fr1[16], fr2[16];
    {
        const float* wrow = Wr + (size_t)(i0 + ct * 16 + c) * NNEUR + h * 512 + kg * 8;
        #pragma unroll
        for (int ks = 0; ks < 16; ++ks) {
            float4 a = *(const float4*)(wrow + ks * 32);
            float4 b = *(const float4*)(wrow + ks * 32 + 4);
            float fv[8] = {a.x, a.y, a.z, a.w, b.x, b.y, b.z, b.w};
            S8 vh, vm, vl;
            #pragma unroll
            for (int e = 0; e < 8; ++e) {
                float fw = fv[e];
                unsigned short hb = f2bf_rn(fw);
                float hf = __uint_as_float((unsigned)hb << 16);
                float rm = fw - hf;                     // exact (Sterbenz)
                unsigned short mb = f2bf_rn(rm);
                float mf = __uint_as_float((unsigned)mb << 16);
                float rl = rm - mf;                     // exact; fits bf16
                vh.us[e] = hb; vm.us[e] = mb; vl.us[e] = f2bf_rn(rl);
            }
            fr0[ks] = vh.s; fr1[ks] = vm.s; fr2[ks] = vl.s;
        }
    }
    __syncthreads();

    const float brv = br[i0 + ct * 16 + c];
    float vreg[4] = {0.f, 0.f, 0.f, 0.f};
    const size_t BN = (size_t)BATCH * NNEUR;

    // poll geometry: thread owns qwords 2*tid, 2*tid+1 (col = tid>>2, pairs p0, p0+1)
    const int pcol = tid >> 2;          // producer column 0..63
    const int pp0  = (2 * tid) & 7;     // first rowpair (even) 0,2,4,6

    for (int t = 0; t < T_STEPS; ++t) {
        float txv[4];
        if (h == 0) {
            #pragma unroll
            for (int j = 0; j < 4; ++j)
                txv[j] = tx[(size_t)t * BN + (size_t)(b0 + kg * 4 + j) * NNEUR + i0 + ct * 16 + c];
        }

        // ---- stage spikes of step t-1: paired-qword 16B poll + guarded 8B retry ----
        if (t > 0) {
            const unsigned long long* qb = qbuf + (size_t)((t - 1) % 3) * 4096 + bb * 512;
            const unsigned want = (unsigned)(t - 1);
            uint4v q;   // [lo0, st0, lo1, st1]
            asm volatile("global_load_dwordx4 %0, %1, off sc0 sc1"
                         : "=&v"(q) : "v"(qb + 2 * tid) : "memory");
            asm volatile("s_waitcnt vmcnt(0)" ::: "memory");
            __builtin_amdgcn_sched_barrier(0);
            unsigned pend = 0;
            if (q.y == want) {
                ys[(2 * pp0)     * 66 + pcol] = (unsigned short)(q.x & 0xFFFFu);
                ys[(2 * pp0 + 1) * 66 + pcol] = (unsigned short)(q.x >> 16);
            } else pend |= 1u;
            if (q.w == want) {
                ys[(2 * pp0 + 2) * 66 + pcol] = (unsigned short)(q.z & 0xFFFFu);
                ys[(2 * pp0 + 3) * 66 + pcol] = (unsigned short)(q.z >> 16);
            } else pend |= 2u;
            while (pend) {
                #pragma unroll
                for (int k = 0; k < 2; ++k) {
                    if (pend & (1u << k)) {
                        unsigned long long qv = __hip_atomic_load(qb + 2 * tid + k,
                                                                  __ATOMIC_RELAXED, __HIP_MEMORY_SCOPE_AGENT);
                        if ((unsigned)(qv >> 32) == want) {
                            int p = pp0 + k;
                            ys[(2 * p)     * 66 + pcol] = (unsigned short)(qv & 0xFFFFu);
                            ys[(2 * p + 1) * 66 + pcol] = (unsigned short)((qv >> 16) & 0xFFFFu);
                            pend &= ~(1u << k);
                        }
                    }
                }
                if (pend) __builtin_amdgcn_s_sleep(1);
            }
        }
        __syncthreads();

        f32x4 acc = {0.f, 0.f, 0.f, 0.f};
        if (t > 0) {
            // A-frags: bf16 1.0 / 0.0 bit patterns (identical to rounds 2/5/6/14/16/20)
            short8 afr[16];
            #pragma unroll
            for (int ks = 0; ks < 16; ++ks) {
                unsigned wv = *(const unsigned*)(ys + c * 66 + 2 * (h * 16 + ks));
                unsigned byt = (wv >> (kg * 8)) & 0xFFu;
                FU f;
                #pragma unroll
                for (int q2 = 0; q2 < 4; ++q2) {
                    f.u[q2] = (((byt >> (2 * q2)) & 1u) ? 0x00003F80u : 0u)
                            | (((byt >> (2 * q2 + 1)) & 1u) ? 0x3F800000u : 0u);
                }
                afr[ks] = f.s;
            }
            // single accumulator chain, mat-outer / ks-inner — proven exact order
            #pragma unroll
            for (int ks = 0; ks < 16; ++ks)
                acc = __builtin_amdgcn_mfma_f32_16x16x32_bf16(afr[ks], fr0[ks], acc, 0, 0, 0);
            #pragma unroll
            for (int ks = 0; ks < 16; ++ks)
                acc = __builtin_amdgcn_mfma_f32_16x16x32_bf16(afr[ks], fr1[ks], acc, 0, 0, 0);
            #pragma unroll
            for (int ks = 0; ks < 16; ++ks)
                acc = __builtin_amdgcn_mfma_f32_16x16x32_bf16(afr[ks], fr2[ks], acc, 0, 0, 0);
        }

        if (h == 1) {
            #pragma unroll
            for (int j = 0; j < 4; ++j)
                red[ct * 256 + (kg * 4 + j) * 16 + c] = acc[j];
        }
        __syncthreads();

        if (h == 0) {
            float* op = out + (size_t)t * BN;
            unsigned long long* pq = qbuf + (size_t)(t % 3) * 4096 + bb * 512;
            int sp4[4];
            unsigned long long mball[4];
            #pragma unroll
            for (int j = 0; j < 4; ++j) {
                float z  = acc[j] + red[ct * 256 + (kg * 4 + j) * 16 + c];
                float x  = (txv[j] + z) + brv;
                float vv = DECAY_F * vreg[j] + x;
                int   sp = vv > THRESH;
                vreg[j]  = sp ? 0.f : vv;
                sp4[j]   = sp;
                mball[j] = __ballot(sp != 0);
            }
            // publish FIRST: rowpair qwords, col-major layout (flat = col*8 + p)
            if (c == 0 || c == 2) {
                int a = c >> 1;
                unsigned lo = (unsigned)((mball[2 * a]     >> (kg * 16)) & 0xFFFFu);
                unsigned hi = (unsigned)((mball[2 * a + 1] >> (kg * 16)) & 0xFFFFu);
                unsigned long long qv = ((unsigned long long)(unsigned)t << 32)
                                      | ((unsigned long long)hi << 16) | lo;
                atomicExch(&pq[(ib * 2 + ct) * 8 + (kg * 2 + a)], qv);
            }
            // then the out-slab stores (no intra-kernel consumer)
            #pragma unroll
            for (int j = 0; j < 4; ++j)
                op[(size_t)(b0 + kg * 4 + j) * NNEUR + i0 + ct * 16 + c] = sp4[j] ? 1.f : 0.f;
        }
        // no end-of-step barrier: stamp polling is the synchronization
    }
}

extern "C" void kernel_launch(void* const* d_in, const int* in_sizes, int n_in,
                              void* d_out, int out_size, void* d_ws, size_t ws_size,
                              hipStream_t stream)
{
    const float* tx = (const float*)d_in[0];
    const float* Wr = (const float*)d_in[1];
    const float* br = (const float*)d_in[2];
    float* out = (float*)d_out;
    unsigned long long* qbuf = (unsigned long long*)d_ws;   // [3][8][512] u64 = 96 KB

    const int lds_bytes = 2 * 16 * 16 * 4 + 16 * 66 * 2;   // 4160
    hipFuncSetAttribute(reinterpret_cast<const void*>(rlif_persist),
                        hipFuncAttributeMaxDynamicSharedMemorySize, lds_bytes);

    rlif_init<<<dim3(48), dim3(256), 0, stream>>>(qbuf);
    rlif_persist<<<dim3(256), dim3(256), lds_bytes, stream>>>(tx, Wr, br, out, qbuf);
}